// Round 6
// baseline (147.189 us; speedup 1.0000x reference)
//
#include <hip/hip_runtime.h>
#include <hip/hip_bf16.h>

#define DDIM 512
#define NROWS 6144
#define BM 64
#define BN 64
#define BK 32
#define KSTEPS (DDIM / BK)  // 16

typedef __attribute__((ext_vector_type(8))) short short8;
typedef __attribute__((ext_vector_type(4))) float f32x4;

#define GLDS16(g, s)                                          \
  __builtin_amdgcn_global_load_lds(                           \
      (const __attribute__((address_space(1))) void*)(g),     \
      (__attribute__((address_space(3))) void*)(s), 16, 0, 0)

// ---------------------------------------------------------------------------
// Fold the 4 [512,512] k-blocks of W [2048,512] (sum), transpose to Wt[n][k],
// cast bf16.  Vectorized: float4 global reads, ushort4 (4x bf16) writes.
// Tile = 32 k-rows x 64 n-cols; grid (16, 8, 2) = 256 blocks.
// ---------------------------------------------------------------------------
__global__ __launch_bounds__(256) void prep_w(
    const float* __restrict__ Wcc, const float* __restrict__ Wcp,
    __hip_bfloat16* __restrict__ Wt) {
    const float* W = blockIdx.z ? Wcp : Wcc;
    unsigned short* o = (unsigned short*)Wt + (size_t)blockIdx.z * DDIM * DDIM;
    __shared__ float lds[32][65];
    const int k0 = blockIdx.x * 32, n0 = blockIdx.y * 64;
    #pragma unroll
    for (int u = 0; u < 2; ++u) {
        int idx = u * 256 + threadIdx.x;
        int kk = idx >> 4, c = idx & 15;
        float4 s = {0.f, 0.f, 0.f, 0.f};
        #pragma unroll
        for (int i = 0; i < 4; ++i) {
            float4 v = *(const float4*)&W[(size_t)(i * DDIM + k0 + kk) * DDIM + n0 + c * 4];
            s.x += v.x; s.y += v.y; s.z += v.z; s.w += v.w;
        }
        lds[kk][c * 4 + 0] = s.x;
        lds[kk][c * 4 + 1] = s.y;
        lds[kk][c * 4 + 2] = s.z;
        lds[kk][c * 4 + 3] = s.w;
    }
    __syncthreads();
    #pragma unroll
    for (int u = 0; u < 2; ++u) {
        int idx = u * 256 + threadIdx.x;
        int nr = idx >> 3, kc = idx & 7;
        ushort4 p;
        #pragma unroll
        for (int j = 0; j < 4; ++j) {
            __hip_bfloat16 h = __float2bfloat16(lds[kc * 4 + j][nr]);
            ((unsigned short*)&p)[j] = *(unsigned short*)&h;
        }
        *(ushort4*)&o[(size_t)(n0 + nr) * DDIM + k0 + kc * 4] = p;
    }
}

// ---------------------------------------------------------------------------
// C[6144,512] = A_f32 @ W + bias.  Barrier-free K-loop:
//  - B panel (BN=64 cols x 512 k, bf16 = 64 KB) staged ONCE via glds; one
//    vmcnt(4)+s_barrier after, then never again.
//  - Wave-tile = 16 rows x 64 cols (4 waves = BM 64).  Each wave stages ITS
//    OWN 16 A rows (2 glds/stage, f32) into wave-private LDS, double-
//    buffered, counted vmcnt(2) depth-2 chain -> no cross-wave deps, no
//    in-loop barriers.  In-wave WAR (re-stage over read buffer) fenced by
//    lgkmcnt(0)+sched_barrier(0) before STAGE (reads retired; glds write
//    lands >=RTT later).
//  - f32->bf16 cvt of A at fragment read.  4 MFMA/step/wave.
// LDS 64+16=80 KB -> 2 blocks/CU.  Grid (96,8,2)=1536; 96%8==0 so the 8
// n-blocks sharing an A panel map to one XCD -> A re-reads are L2 hits.
// Swizzles (rule #21, pre-swizzled glds source + swizzled read, both 2-way
// = free):  A slot ^= (row&7) on 8x16B rows; B slot ^= (n&7) on 64x16B rows.
// ---------------------------------------------------------------------------
__global__ __launch_bounds__(256, 2) void gemm_bias(
    const float* __restrict__ Aat, const float* __restrict__ Aam,
    const __hip_bfloat16* __restrict__ Wtall,
    const float* __restrict__ bias0, const float* __restrict__ bias1,
    float* __restrict__ C) {
  __shared__ unsigned short Bs[BN * DDIM];  // 64 KB, row = 1 KB
  __shared__ float As[2][BM * BK];          // 2 x 8 KB

  const int z = blockIdx.z;
  const float* A = z ? Aam : Aat;
  const unsigned short* Wt = (const unsigned short*)Wtall + (size_t)z * DDIM * DDIM;
  const float* bias = z ? bias1 : bias0;
  float* Cz = C + (size_t)z * NROWS * DDIM;

  const int tid = threadIdx.x;
  const int w = tid >> 6, l = tid & 63;
  const int lr = l & 15, hi = l >> 4;
  const int m0 = blockIdx.x * BM, n0 = blockIdx.y * BN;

  // ---- B static stage: wave w stages rows [w*16, w*16+16), 1 glds per row.
  // LDS[row][slot s] holds k-chunk s^(row&7)  (chunks of 16 B = 8 bf16).
  #pragma unroll
  for (int r = 0; r < 16; ++r) {
    const int row = w * 16 + r;
    GLDS16(Wt + (size_t)(n0 + row) * DDIM + ((l ^ (row & 7)) << 3),
           &Bs[row * DDIM]);
  }

  // ---- A stage setup: wave-private rows, pre-swizzled source.
  const int ra0 = w * 16 + (l >> 3), ra1 = ra0 + 8;
  const float* srcA0 = A + (size_t)(m0 + ra0) * DDIM + (((l & 7) ^ (ra0 & 7)) << 2);
  const float* srcA1 = A + (size_t)(m0 + ra1) * DDIM + (((l & 7) ^ (ra1 & 7)) << 2);
  const unsigned ldsA0 = (w * 16) * BK, ldsA1 = (w * 16 + 8) * BK;

#define STAGE(buf, kk)                              \
  do {                                              \
    GLDS16(srcA0 + (kk) * BK, &As[buf][ldsA0]);     \
    GLDS16(srcA1 + (kk) * BK, &As[buf][ldsA1]);     \
  } while (0)

  STAGE(0, 0);
  STAGE(1, 1);

  f32x4 acc[4];
  #pragma unroll
  for (int j = 0; j < 4; ++j) acc[j] = (f32x4){0.f, 0.f, 0.f, 0.f};

  // B fully landed (A0/A1 may still fly); one and only barrier.
  asm volatile("s_waitcnt vmcnt(4)" ::: "memory");
  __builtin_amdgcn_s_barrier();

  #pragma unroll
  for (int t = 0; t < KSTEPS; ++t) {
    if (t < KSTEPS - 1)
      asm volatile("s_waitcnt vmcnt(2)" ::: "memory");  // own stage t landed
    else
      asm volatile("s_waitcnt vmcnt(0)" ::: "memory");
    const int buf = t & 1;

    // A fragment: row r (own band), chunks hi*2, hi*2+1 (swizzled)
    const int r = w * 16 + lr;
    f32x4 x0 = *(const f32x4*)&As[buf][r * BK + (((hi * 2 + 0) ^ (lr & 7)) << 2)];
    f32x4 x1 = *(const f32x4*)&As[buf][r * BK + (((hi * 2 + 1) ^ (lr & 7)) << 2)];
    short8 af;
    {
      float xv[8] = {x0[0], x0[1], x0[2], x0[3], x1[0], x1[1], x1[2], x1[3]};
      #pragma unroll
      for (int e = 0; e < 8; ++e) {
        __hip_bfloat16 h = __float2bfloat16(xv[e]);
        af[e] = *(short*)&h;
      }
    }
    #pragma unroll
    for (int tn = 0; tn < 4; ++tn) {
      const int np = tn * 16 + lr;
      const int slot = (t * 4 + hi) ^ (lr & 7);
      short8 bf = *(const short8*)&Bs[np * DDIM + slot * 8];
      acc[tn] = __builtin_amdgcn_mfma_f32_16x16x32_bf16(af, bf, acc[tn], 0, 0, 0);
    }

    if (t + 2 < KSTEPS) {
      // WAR fence: all ds_reads of buf retired before glds overwrites it.
      asm volatile("s_waitcnt lgkmcnt(0)" ::: "memory");
      __builtin_amdgcn_sched_barrier(0);
      STAGE(buf, t + 2);
    }
  }

  // ---- epilogue: 16 rows x 64 cols per wave
  #pragma unroll
  for (int tn = 0; tn < 4; ++tn) {
    const int col = n0 + tn * 16 + lr;
    const float bv = bias[col];
    #pragma unroll
    for (int rr = 0; rr < 4; ++rr)
      Cz[(size_t)(m0 + w * 16 + hi * 4 + rr) * DDIM + col] = acc[tn][rr] + bv;
  }
#undef STAGE
}

extern "C" void kernel_launch(void* const* d_in, const int* in_sizes, int n_in,
                              void* d_out, int out_size, void* d_ws, size_t ws_size,
                              hipStream_t stream) {
    const float* atoms = (const float*)d_in[0];   // [6144,512]
    const float* amino = (const float*)d_in[1];   // [6144,512]
    const float* Wcc   = (const float*)d_in[15];  // [2048,512]
    const float* bcc   = (const float*)d_in[16];  // [512]
    const float* Wcp   = (const float*)d_in[17];  // [2048,512]
    const float* bcp   = (const float*)d_in[18];  // [512]
    float* out = (float*)d_out;

    __hip_bfloat16* Wt = (__hip_bfloat16*)d_ws;   // [2][512][512] bf16 = 1 MB

    dim3 fgrid(DDIM / 32, DDIM / 64, 2);
    prep_w<<<fgrid, 256, 0, stream>>>(Wcc, Wcp, Wt);

    dim3 ggrid(NROWS / BM, DDIM / BN, 2);
    gemm_bias<<<ggrid, 256, 0, stream>>>(atoms, amino, Wt, bcc, bcp, out);
}

// Round 7
// 143.975 us; speedup vs baseline: 1.0223x; 1.0223x over previous
//
#include <hip/hip_runtime.h>
#include <hip/hip_bf16.h>

#define DDIM 512
#define NROWS 6144
#define BM 64
#define BN 64
#define BK 32
#define KSTEPS 16

typedef __attribute__((ext_vector_type(8))) short short8;
typedef __attribute__((ext_vector_type(4))) float f32x4;

#define GLDS16(g, s)                                          \
  __builtin_amdgcn_global_load_lds(                           \
      (const __attribute__((address_space(1))) void*)(g),     \
      (__attribute__((address_space(3))) void*)(s), 16, 0, 0)

// ---------------------------------------------------------------------------
// Fold the 4 [512,512] k-blocks of W [2048,512] (sum), transpose to Wt[n][k],
// cast bf16.  Vectorized: float4 global reads, ushort4 (4x bf16) writes.
// Tile = 32 k-rows x 64 n-cols; grid (16, 8, 2) = 256 blocks.
// ---------------------------------------------------------------------------
__global__ __launch_bounds__(256) void prep_w(
    const float* __restrict__ Wcc, const float* __restrict__ Wcp,
    __hip_bfloat16* __restrict__ Wt) {
    const float* W = blockIdx.z ? Wcp : Wcc;
    unsigned short* o = (unsigned short*)Wt + (size_t)blockIdx.z * DDIM * DDIM;
    __shared__ float lds[32][65];
    const int k0 = blockIdx.x * 32, n0 = blockIdx.y * 64;
    #pragma unroll
    for (int u = 0; u < 2; ++u) {
        int idx = u * 256 + threadIdx.x;
        int kk = idx >> 4, c = idx & 15;
        float4 s = {0.f, 0.f, 0.f, 0.f};
        #pragma unroll
        for (int i = 0; i < 4; ++i) {
            float4 v = *(const float4*)&W[(size_t)(i * DDIM + k0 + kk) * DDIM + n0 + c * 4];
            s.x += v.x; s.y += v.y; s.z += v.z; s.w += v.w;
        }
        lds[kk][c * 4 + 0] = s.x;
        lds[kk][c * 4 + 1] = s.y;
        lds[kk][c * 4 + 2] = s.z;
        lds[kk][c * 4 + 3] = s.w;
    }
    __syncthreads();
    #pragma unroll
    for (int u = 0; u < 2; ++u) {
        int idx = u * 256 + threadIdx.x;
        int nr = idx >> 3, kc = idx & 7;
        ushort4 p;
        #pragma unroll
        for (int j = 0; j < 4; ++j) {
            __hip_bfloat16 h = __float2bfloat16(lds[kc * 4 + j][nr]);
            ((unsigned short*)&p)[j] = *(unsigned short*)&h;
        }
        *(ushort4*)&o[(size_t)(n0 + nr) * DDIM + k0 + kc * 4] = p;
    }
}

// ---------------------------------------------------------------------------
// C[6144,512] = A_f32 @ W + bias.  R4's 3-buffer counted-vmcnt schedule,
// upgraded: A is reg-staged bf16 (global float4 -> cvt in stage phase ->
// one swizzled ds_write_b128), B stays glds.  64x64 tile, 4 waves
// (wave-tile 32x32), LDS 3x(4+4)=24 KB -> grid (96,8,2)=1536 blocks =
// 6/CU = 24 waves/CU, all co-resident.
// Per-stage vmem ops: A loads x2 + B glds x1 = 3; depth 2 -> vmcnt(3)
// waits exactly stage t (vmcnt(0) at the tail).  A-prefetch for t+2 issues
// PRE-barrier (register-only, no LDS hazard); B glds POST-barrier (its
// target buffer's last readers passed barrier t after compute(t-1) -- MFMA
// operand-waits guarantee those ds_reads completed).  ds_write -> explicit
// lgkmcnt(0) before s_barrier (raw barrier doesn't drain).
// Swizzles (64 B rows = 4 x 16 B slots): slot ^= ((row>>1)&3); 16 lanes of a
// fragment read cover 8 slot-columns -> 2-way = free.  Same XOR on the
// pre-swizzled B glds source and the A ds_write address.
// grid.y=8, 96%8==0 -> the 8 n-blocks sharing an A panel sit on one XCD.
// ---------------------------------------------------------------------------
__global__ __launch_bounds__(256, 6) void gemm_bias(
    const float* __restrict__ Aat, const float* __restrict__ Aam,
    const __hip_bfloat16* __restrict__ Wtall,
    const float* __restrict__ bias0, const float* __restrict__ bias1,
    float* __restrict__ C) {
  __shared__ unsigned short As[3][BM * BK];  // bf16, 4 KB per buffer
  __shared__ unsigned short Bs[3][BN * BK];  // bf16, 4 KB per buffer

  const int z = blockIdx.z;
  const float* A = z ? Aam : Aat;
  const unsigned short* Wt = (const unsigned short*)Wtall + (size_t)z * DDIM * DDIM;
  const float* bias = z ? bias1 : bias0;
  float* Cz = C + (size_t)z * NROWS * DDIM;

  const int tid = threadIdx.x;
  const int w = tid >> 6, l = tid & 63;
  const int lr = l & 15, hi = l >> 4;
  const int wm = w >> 1, wn = w & 1;
  const int m0 = blockIdx.x * BM, n0 = blockIdx.y * BN;

  // stage mapping: wave w stages rows [w*16, w*16+16); lane -> (row, chunk)
  const int sr = w * 16 + (l >> 2);
  const int sc = l & 3;
  const float* srcA = A + (size_t)(m0 + sr) * DDIM + sc * 8;
  const unsigned short* srcB =
      Wt + (size_t)(n0 + sr) * DDIM + ((sc ^ ((sr >> 1) & 3)) << 3);
  const unsigned ldsB = (unsigned)(w * 16 * BK);  // wave-uniform glds base
  const unsigned wrA = (unsigned)(sr * BK + ((sc ^ ((sr >> 1) & 3)) << 3));

  // fragment LDS addresses (ushort index)
  const int ar0 = wm * 32 + lr, ar1 = ar0 + 16;
  const int br0 = wn * 32 + lr, br1 = br0 + 16;
  const unsigned adA0 = ar0 * BK + ((hi ^ ((ar0 >> 1) & 3)) << 3);
  const unsigned adA1 = ar1 * BK + ((hi ^ ((ar1 >> 1) & 3)) << 3);
  const unsigned adB0 = br0 * BK + ((hi ^ ((br0 >> 1) & 3)) << 3);
  const unsigned adB1 = br1 * BK + ((hi ^ ((br1 >> 1) & 3)) << 3);

  f32x4 acc[2][2];
  #pragma unroll
  for (int i = 0; i < 2; ++i)
    #pragma unroll
    for (int j = 0; j < 2; ++j) acc[i][j] = (f32x4){0.f, 0.f, 0.f, 0.f};

  float4 rA[2][2];  // two in-flight A stages (indices unroll-constant)

  // prologue: issue stages 0 and 1 (order defines vmcnt counting: A,A,B each)
  rA[0][0] = *(const float4*)(srcA + 0 * BK);
  rA[0][1] = *(const float4*)(srcA + 0 * BK + 4);
  GLDS16(srcB + 0 * BK, &Bs[0][ldsB]);
  rA[1][0] = *(const float4*)(srcA + 1 * BK);
  rA[1][1] = *(const float4*)(srcA + 1 * BK + 4);
  GLDS16(srcB + 1 * BK, &Bs[1][ldsB]);

  #pragma unroll
  for (int t = 0; t < KSTEPS; ++t) {
    if (t < KSTEPS - 1)
      asm volatile("s_waitcnt vmcnt(3)" ::: "memory");  // stage t landed
    else
      asm volatile("s_waitcnt vmcnt(0)" ::: "memory");

    // cvt + single swizzled ds_write of own A stage-t rows (bf16)
    {
      const float4 x0 = rA[t & 1][0], x1 = rA[t & 1][1];
      const float xv[8] = {x0.x, x0.y, x0.z, x0.w, x1.x, x1.y, x1.z, x1.w};
      short8 av;
      #pragma unroll
      for (int e = 0; e < 8; ++e) {
        __hip_bfloat16 h = __float2bfloat16(xv[e]);
        av[e] = *(short*)&h;
      }
      *(short8*)&As[t % 3][wrA] = av;
    }
    // A prefetch for stage t+2 (register-only -> safe before the barrier)
    if (t + 2 < KSTEPS) {
      rA[t & 1][0] = *(const float4*)(srcA + (t + 2) * BK);
      rA[t & 1][1] = *(const float4*)(srcA + (t + 2) * BK + 4);
    }
    asm volatile("s_waitcnt lgkmcnt(0)" ::: "memory");  // drain ds_write
    __builtin_amdgcn_s_barrier();
    if (t + 2 < KSTEPS)
      GLDS16(srcB + (t + 2) * BK, &Bs[(t + 2) % 3][ldsB]);

    // compute step t: 4 ds_read_b128 + 4 MFMA
    short8 af0 = *(const short8*)&As[t % 3][adA0];
    short8 af1 = *(const short8*)&As[t % 3][adA1];
    short8 bf0 = *(const short8*)&Bs[t % 3][adB0];
    short8 bf1 = *(const short8*)&Bs[t % 3][adB1];
    acc[0][0] = __builtin_amdgcn_mfma_f32_16x16x32_bf16(af0, bf0, acc[0][0], 0, 0, 0);
    acc[0][1] = __builtin_amdgcn_mfma_f32_16x16x32_bf16(af0, bf1, acc[0][1], 0, 0, 0);
    acc[1][0] = __builtin_amdgcn_mfma_f32_16x16x32_bf16(af1, bf0, acc[1][0], 0, 0, 0);
    acc[1][1] = __builtin_amdgcn_mfma_f32_16x16x32_bf16(af1, bf1, acc[1][1], 0, 0, 0);
  }

  // epilogue: wave-tile 32x32
  #pragma unroll
  for (int tn = 0; tn < 2; ++tn) {
    const int col = n0 + wn * 32 + tn * 16 + lr;
    const float bv = bias[col];
    #pragma unroll
    for (int tm = 0; tm < 2; ++tm) {
      const int row = m0 + wm * 32 + tm * 16 + hi * 4;
      #pragma unroll
      for (int r = 0; r < 4; ++r)
        Cz[(size_t)(row + r) * DDIM + col] = acc[tm][tn][r] + bv;
    }
  }
}

extern "C" void kernel_launch(void* const* d_in, const int* in_sizes, int n_in,
                              void* d_out, int out_size, void* d_ws, size_t ws_size,
                              hipStream_t stream) {
    const float* atoms = (const float*)d_in[0];   // [6144,512]
    const float* amino = (const float*)d_in[1];   // [6144,512]
    const float* Wcc   = (const float*)d_in[15];  // [2048,512]
    const float* bcc   = (const float*)d_in[16];  // [512]
    const float* Wcp   = (const float*)d_in[17];  // [2048,512]
    const float* bcp   = (const float*)d_in[18];  // [512]
    float* out = (float*)d_out;

    __hip_bfloat16* Wt = (__hip_bfloat16*)d_ws;   // [2][512][512] bf16 = 1 MB

    dim3 fgrid(DDIM / 32, DDIM / 64, 2);
    prep_w<<<fgrid, 256, 0, stream>>>(Wcc, Wcp, Wt);

    dim3 ggrid(NROWS / BM, DDIM / BN, 2);
    gemm_bias<<<ggrid, 256, 0, stream>>>(atoms, amino, Wt, bcc, bcp, out);
}

// Round 9
// 133.825 us; speedup vs baseline: 1.0999x; 1.0758x over previous
//
#include <hip/hip_runtime.h>
#include <hip/hip_bf16.h>

#define DDIM 512
#define NROWS 6144
#define BM 64
#define BN 128
#define BK 32
#define KSTEPS (DDIM / BK)  // 16

typedef __attribute__((ext_vector_type(8))) short short8;
typedef __attribute__((ext_vector_type(4))) float f32x4;

#define GLDS16(g, s)                                          \
  __builtin_amdgcn_global_load_lds(                           \
      (const __attribute__((address_space(1))) void*)(g),     \
      (__attribute__((address_space(3))) void*)(s), 16, 0, 0)

// ---------------------------------------------------------------------------
// Fold the 4 [512,512] k-blocks of W [2048,512] (sum), transpose to Wt[n][k],
// cast bf16.  Vectorized: float4 global reads, ushort4 (4x bf16) writes.
// Tile = 32 k-rows x 64 n-cols; grid (16, 8, 2) = 256 blocks.
// ---------------------------------------------------------------------------
__global__ __launch_bounds__(256) void prep_w(
    const float* __restrict__ Wcc, const float* __restrict__ Wcp,
    __hip_bfloat16* __restrict__ Wt) {
    const float* W = blockIdx.z ? Wcp : Wcc;
    unsigned short* o = (unsigned short*)Wt + (size_t)blockIdx.z * DDIM * DDIM;
    __shared__ float lds[32][65];
    const int k0 = blockIdx.x * 32, n0 = blockIdx.y * 64;
    #pragma unroll
    for (int u = 0; u < 2; ++u) {
        int idx = u * 256 + threadIdx.x;
        int kk = idx >> 4, c = idx & 15;
        float4 s = {0.f, 0.f, 0.f, 0.f};
        #pragma unroll
        for (int i = 0; i < 4; ++i) {
            float4 v = *(const float4*)&W[(size_t)(i * DDIM + k0 + kk) * DDIM + n0 + c * 4];
            s.x += v.x; s.y += v.y; s.z += v.z; s.w += v.w;
        }
        lds[kk][c * 4 + 0] = s.x;
        lds[kk][c * 4 + 1] = s.y;
        lds[kk][c * 4 + 2] = s.z;
        lds[kk][c * 4 + 3] = s.w;
    }
    __syncthreads();
    #pragma unroll
    for (int u = 0; u < 2; ++u) {
        int idx = u * 256 + threadIdx.x;
        int nr = idx >> 3, kc = idx & 7;
        ushort4 p;
        #pragma unroll
        for (int j = 0; j < 4; ++j) {
            __hip_bfloat16 h = __float2bfloat16(lds[kc * 4 + j][nr]);
            ((unsigned short*)&p)[j] = *(unsigned short*)&h;
        }
        *(ushort4*)&o[(size_t)(n0 + nr) * DDIM + k0 + kc * 4] = p;
    }
}

// ---------------------------------------------------------------------------
// C[6144,512] = A_f32 @ W + bias.  T3/T4-lite: 3-buffer LDS, prefetch depth
// 2, ONE raw s_barrier per K-step, counted `s_waitcnt vmcnt(4)` (4 glds per
// stage; stages t,t+1 in flight -> vmcnt(4) waits exactly stage t).  Race
// safety: STAGE(t+2) writes buffer (t-1)%3, freed because every wave passed
// COMPUTE(t-1) before the iter-t barrier; vmcnt-before-barrier makes all
// waves' stage-t loads LDS-visible.  f32->bf16 cvt of A at fragment read.
// Tile 64x128, 4 waves (wave tile 32x64).  Grid (96,4,2) = 768 = 3/CU.
// Swizzle (rule #21): linear glds dest + pre-swizzled source + swizzled read.
//   A row = 128 B = 8 slots, slot ^= (row & 7)        -> 2-way (free)
//   B row =  64 B = 4 slots, slot ^= ((row>>1) & 3)   -> 2-way (free)
// ---------------------------------------------------------------------------
__global__ __launch_bounds__(256, 3) void gemm_bias(
    const float* __restrict__ Aat, const float* __restrict__ Aam,
    const __hip_bfloat16* __restrict__ Wtall,
    const float* __restrict__ bias0, const float* __restrict__ bias1,
    float* __restrict__ C) {
  __shared__ float As[3][BM * BK];           // 3 x 8 KB
  __shared__ unsigned short Bs[3][BN * BK];  // 3 x 8 KB

  const int z = blockIdx.z;
  const float* A = z ? Aam : Aat;
  const unsigned short* Wt = (const unsigned short*)Wtall + (size_t)z * DDIM * DDIM;
  const float* bias = z ? bias1 : bias0;
  float* Cz = C + (size_t)z * NROWS * DDIM;

  const int tid = threadIdx.x;
  const int w = tid >> 6, l = tid & 63;
  const int m0 = blockIdx.x * BM;
  const int n0 = blockIdx.y * BN;

  // staging sources (pre-swizzled) + wave-uniform LDS offsets
  const float* srcA0;
  const float* srcA1;
  const unsigned short* srcB0;
  const unsigned short* srcB1;
  {
    int r0 = w * 16 + (l >> 3);           // A instr 0: rows w*16 .. +7
    int r1 = r0 + 8;                      // A instr 1
    srcA0 = A + (size_t)(m0 + r0) * DDIM + (((l & 7) ^ (r0 & 7)) << 2);
    srcA1 = A + (size_t)(m0 + r1) * DDIM + (((l & 7) ^ (r1 & 7)) << 2);
    int q0 = w * 32 + (l >> 2);           // B instr 0: rows w*32 .. +15
    int q1 = q0 + 16;                     // B instr 1
    srcB0 = Wt + (size_t)(n0 + q0) * DDIM + (((l & 3) ^ ((q0 >> 1) & 3)) << 3);
    srcB1 = Wt + (size_t)(n0 + q1) * DDIM + (((l & 3) ^ ((q1 >> 1) & 3)) << 3);
  }
  const unsigned ldsA0 = (w * 2 + 0) * 256, ldsA1 = (w * 2 + 1) * 256;
  const unsigned ldsB0 = (w * 2 + 0) * 512, ldsB1 = (w * 2 + 1) * 512;

#define STAGE(buf, kk)                                 \
  do {                                                 \
    GLDS16(srcA0 + (kk) * BK, &As[buf][ldsA0]);        \
    GLDS16(srcA1 + (kk) * BK, &As[buf][ldsA1]);        \
    GLDS16(srcB0 + (kk) * BK, &Bs[buf][ldsB0]);        \
    GLDS16(srcB1 + (kk) * BK, &Bs[buf][ldsB1]);        \
  } while (0)

  f32x4 acc[2][4];
  #pragma unroll
  for (int i = 0; i < 2; ++i)
    #pragma unroll
    for (int j = 0; j < 4; ++j) acc[i][j] = (f32x4){0.f, 0.f, 0.f, 0.f};

  const int s0 = (l >> 4) * 2;   // A 16B-slot pair base (k-group)
  const int bs = (l >> 4);       // B 16B slot (k-group)
  const int lr = l & 15;

#define COMPUTE(buf)                                                          \
  do {                                                                        \
    short8 afr[2];                                                            \
    _Pragma("unroll")                                                         \
    for (int tm = 0; tm < 2; ++tm) {                                          \
      int r = (w >> 1) * 32 + tm * 16 + lr;                                   \
      f32x4 x0 = *(const f32x4*)&As[buf][r * BK + (((s0 + 0) ^ (r & 7)) << 2)]; \
      f32x4 x1 = *(const f32x4*)&As[buf][r * BK + (((s0 + 1) ^ (r & 7)) << 2)]; \
      float xv[8] = {x0[0], x0[1], x0[2], x0[3], x1[0], x1[1], x1[2], x1[3]}; \
      _Pragma("unroll")                                                       \
      for (int e = 0; e < 8; ++e) {                                           \
        __hip_bfloat16 h = __float2bfloat16(xv[e]);                           \
        afr[tm][e] = *(short*)&h;                                             \
      }                                                                       \
    }                                                                         \
    _Pragma("unroll")                                                         \
    for (int tn = 0; tn < 4; ++tn) {                                          \
      int r = (w & 1) * 64 + tn * 16 + lr;                                    \
      short8 bf = *(const short8*)&Bs[buf][r * BK + ((bs ^ ((r >> 1) & 3)) << 3)]; \
      acc[0][tn] = __builtin_amdgcn_mfma_f32_16x16x32_bf16(afr[0], bf, acc[0][tn], 0, 0, 0); \
      acc[1][tn] = __builtin_amdgcn_mfma_f32_16x16x32_bf16(afr[1], bf, acc[1][tn], 0, 0, 0); \
    }                                                                         \
  } while (0)

  // prologue: two stages in flight
  STAGE(0, 0);
  STAGE(1, 1);

  #pragma unroll
  for (int t = 0; t < KSTEPS; ++t) {
    if (t < KSTEPS - 1)
      asm volatile("s_waitcnt vmcnt(4)" ::: "memory");   // stage t done
    else
      asm volatile("s_waitcnt vmcnt(0)" ::: "memory");   // last stage
    __builtin_amdgcn_s_barrier();
    if (t + 2 < KSTEPS) STAGE((t + 2) % 3, t + 2);
    COMPUTE(t % 3);
  }

  // epilogue
  const int rg = (l >> 4) * 4;
  #pragma unroll
  for (int tn = 0; tn < 4; ++tn) {
    const int col = n0 + (w & 1) * 64 + tn * 16 + lr;
    const float bv = bias[col];
    #pragma unroll
    for (int tm = 0; tm < 2; ++tm) {
      const int row = m0 + (w >> 1) * 32 + tm * 16 + rg;
      #pragma unroll
      for (int r = 0; r < 4; ++r)
        Cz[(size_t)(row + r) * DDIM + col] = acc[tm][tn][r] + bv;
    }
  }
#undef STAGE
#undef COMPUTE
}

extern "C" void kernel_launch(void* const* d_in, const int* in_sizes, int n_in,
                              void* d_out, int out_size, void* d_ws, size_t ws_size,
                              hipStream_t stream) {
    const float* atoms = (const float*)d_in[0];   // [6144,512]
    const float* amino = (const float*)d_in[1];   // [6144,512]
    const float* Wcc   = (const float*)d_in[15];  // [2048,512]
    const float* bcc   = (const float*)d_in[16];  // [512]
    const float* Wcp   = (const float*)d_in[17];  // [2048,512]
    const float* bcp   = (const float*)d_in[18];  // [512]
    float* out = (float*)d_out;

    __hip_bfloat16* Wt = (__hip_bfloat16*)d_ws;   // [2][512][512] bf16 = 1 MB

    dim3 fgrid(DDIM / 32, DDIM / 64, 2);
    prep_w<<<fgrid, 256, 0, stream>>>(Wcc, Wcp, Wt);

    dim3 ggrid(NROWS / BM, DDIM / BN, 2);
    gemm_bias<<<ggrid, 256, 0, stream>>>(atoms, amino, Wt, bcc, bcp, out);
}